// Round 3
// baseline (1334.917 us; speedup 1.0000x reference)
//
#include <hip/hip_runtime.h>

#define NB 131072
#define ND 512
#define NK 64
#define NCB 1024

#define TPB 256
#define RPB2 128            // rows per block (2 threads per row)
#define CHF 4096            // floats per 16 KB chunk (64 rows/entries x 64)

#if defined(__has_builtin)
#if __has_builtin(__builtin_amdgcn_global_load_lds)
#define HAS_GLL 1
#else
#define HAS_GLL 0
#endif
#else
#define HAS_GLL 0
#endif

// ---------------------------------------------------------------------------
// Precompute: C_dec[c][d] = sum_k cb[c,k] * U[d,k]   (decoded codebook, 2 MB)
//             c_sq[c]     = ||cb[c]||^2
// (unchanged from the passing kernel)
// ---------------------------------------------------------------------------
__global__ __launch_bounds__(256) void vq_precompute(
    const float* __restrict__ U, const float* __restrict__ cb,
    float* __restrict__ C_dec, float* __restrict__ c_sq)
{
    int t = blockIdx.x * 256 + threadIdx.x;   // 0 .. NCB*ND-1
    int c = t >> 9;                           // uniform within block
    int d = t & (ND - 1);
    const float* __restrict__ crow = cb + (size_t)c * NK;
    const float* __restrict__ urow = U + (size_t)d * NK;
    float a0 = 0.f, a1 = 0.f, a2 = 0.f, a3 = 0.f;
#pragma unroll
    for (int k = 0; k < NK; k += 4) {
        a0 = fmaf(crow[k + 0], urow[k + 0], a0);
        a1 = fmaf(crow[k + 1], urow[k + 1], a1);
        a2 = fmaf(crow[k + 2], urow[k + 2], a2);
        a3 = fmaf(crow[k + 3], urow[k + 3], a3);
    }
    C_dec[t] = (a0 + a1) + (a2 + a3);
    if (d == 0) {
        float s0 = 0.f, s1 = 0.f, s2 = 0.f, s3 = 0.f;
#pragma unroll
        for (int k = 0; k < NK; k += 4) {
            s0 = fmaf(crow[k + 0], crow[k + 0], s0);
            s1 = fmaf(crow[k + 1], crow[k + 1], s1);
            s2 = fmaf(crow[k + 2], crow[k + 2], s2);
            s3 = fmaf(crow[k + 3], crow[k + 3], s3);
        }
        c_sq[c] = (s0 + s1) + (s2 + s3);
    }
}

// macro: one k-step of the 4 v1-identical chains for one entry
#define CHAINS(A0, A1, A2, A3, CV)            \
    A0 = fmaf(z[k + 0], CV.x, A0);            \
    A1 = fmaf(z[k + 1], CV.y, A1);            \
    A2 = fmaf(z[k + 2], CV.z, A2);            \
    A3 = fmaf(z[k + 3], CV.w, A3);

// macro: finish one entry (v1-identical combine + strict-< first-min)
#define FIN(A0, A1, A2, A3, II)               \
    {                                         \
        float dot = (A0 + A1) + (A2 + A3);    \
        int j = c * 64 + eb + (II);           \
        float dist = fmaf(-2.f, dot, csq_lds[j]); \
        if (dist < best) { best = dist; bidx = j; } \
    }

// ---------------------------------------------------------------------------
// Main v4: v3 skeleton; phase B restructured to 4-entry groups (16 chains),
// cb staging via global_load_lds (no staging VGPRs). All distance math
// bitwise-identical to v1.
// ---------------------------------------------------------------------------
__global__ __launch_bounds__(256, 2) void vq_main4(
    const float* __restrict__ x, const float* __restrict__ U,
    const float* __restrict__ cb, const float* __restrict__ c_sq,
    const float* __restrict__ C_dec, float* __restrict__ out)
{
    __shared__ __align__(16) float buf[2][CHF];   // 32 KB staging, dbuf
    __shared__ float csq_lds[NCB];                // 4 KB
    __shared__ int   s_idx[RPB2];                 // 0.5 KB

    const int tid = threadIdx.x;
    const size_t rowb = (size_t)blockIdx.x * RPB2;

    float* const out_rec = out;                                   // B*D
    float* const out_z   = out + (size_t)NB * ND;                 // B*K
    float* const out_zq  = out_z + (size_t)NB * NK;               // B*K
    float* const out_idx = out_zq + (size_t)NB * NK;              // B

    // ---- prologue: stage c_sq and U chunk 0 ----
#pragma unroll
    for (int i = 0; i < 4; ++i) csq_lds[i * 256 + tid] = c_sq[i * 256 + tid];
    {
        const float4* s4 = (const float4*)U;
        float4* d4 = (float4*)&buf[0][0];
        float4 t0 = s4[0 * 256 + tid], t1 = s4[1 * 256 + tid],
               t2 = s4[2 * 256 + tid], t3 = s4[3 * 256 + tid];
        d4[0 * 256 + tid] = t0; d4[1 * 256 + tid] = t1;
        d4[2 * 256 + tid] = t2; d4[3 * 256 + tid] = t3;
    }
    __syncthreads();

    float z[NK];
#pragma unroll
    for (int j = 0; j < NK; ++j) z[j] = 0.f;

    // ---- phase A (v3-verbatim): A-threads compute z; B-threads stage ----
    for (int dc = 0; dc < 8; ++dc) {
        const int cur = dc & 1;
        if (tid >= 128) {
            const int tB = tid - 128;
            const float4* s4 =
                (const float4*)((dc < 7) ? (U + (size_t)(dc + 1) * CHF) : cb);
            float4* d4 = (float4*)&buf[cur ^ 1][0];
#pragma unroll
            for (int h = 0; h < 2; ++h) {
                float4 t0 = s4[(h * 4 + 0) * 128 + tB];
                float4 t1 = s4[(h * 4 + 1) * 128 + tB];
                float4 t2 = s4[(h * 4 + 2) * 128 + tB];
                float4 t3 = s4[(h * 4 + 3) * 128 + tB];
                d4[(h * 4 + 0) * 128 + tB] = t0;
                d4[(h * 4 + 1) * 128 + tB] = t1;
                d4[(h * 4 + 2) * 128 + tB] = t2;
                d4[(h * 4 + 3) * 128 + tB] = t3;
            }
        } else {
            const float* bufc = &buf[cur][0];
            const float4* x4 = (const float4*)(x + (rowb + tid) * ND);
#pragma unroll 2
            for (int k4 = 0; k4 < 16; ++k4) {
                float4 xv = x4[dc * 16 + k4];
                float xc[4] = {xv.x, xv.y, xv.z, xv.w};
                const float* u = bufc + k4 * 4 * NK;
                // ascending d, ascending j: bitwise == v1's z chain
#pragma unroll
                for (int dd = 0; dd < 4; ++dd) {
#pragma unroll
                    for (int q = 0; q < 16; ++q) {
                        float4 uv = *(const float4*)(u + 4 * q);
                        z[4 * q + 0] = fmaf(uv.x, xc[dd], z[4 * q + 0]);
                        z[4 * q + 1] = fmaf(uv.y, xc[dd], z[4 * q + 1]);
                        z[4 * q + 2] = fmaf(uv.z, xc[dd], z[4 * q + 2]);
                        z[4 * q + 3] = fmaf(uv.w, xc[dd], z[4 * q + 3]);
                    }
                    u += NK;
                }
            }
        }
        __syncthreads();
    }

    // ---- A publishes z (this IS the z output); B picks it up bit-exactly ----
    if (tid < 128) {
        float4* zd = (float4*)(out_z + (rowb + tid) * NK);
#pragma unroll
        for (int q = 0; q < 16; ++q)
            zd[q] = make_float4(z[4 * q], z[4 * q + 1], z[4 * q + 2], z[4 * q + 3]);
    }
    __syncthreads();   // drains vmcnt; same block -> same CU/L2: reads are safe
    if (tid >= 128) {
        const float4* zs = (const float4*)(out_z + (rowb + tid - 128) * NK);
#pragma unroll
        for (int q = 0; q < 16; ++q) {
            float4 v = zs[q];
            z[4 * q + 0] = v.x; z[4 * q + 1] = v.y;
            z[4 * q + 2] = v.z; z[4 * q + 3] = v.w;
        }
    }

    // ---- phase B: 4-entry groups, 16 independent chains, dbuf staging ----
    const int e0 = (tid < 128) ? 0 : 32;   // wave-uniform half-split
    float best = 3.4e38f;
    int bidx = 0;
    for (int c = 0; c < 16; ++c) {
        const int cur = c & 1;
        // ---- issue next chunk's staging EARLY (hides under this chunk) ----
#if HAS_GLL
        if (c < 15) {
            const float* src = cb + (size_t)(c + 1) * CHF;
#pragma unroll
            for (int i = 0; i < 4; ++i) {
                const float* g = src + i * 1024 + tid * 4;
                // wave-uniform LDS base + lane*16B == flat (i*1024 + tid*4)
                float* l = &buf[cur ^ 1][i * 1024 + (tid >> 6) * 256];
                __builtin_amdgcn_global_load_lds(
                    (const __attribute__((address_space(1))) unsigned int*)g,
                    (__attribute__((address_space(3))) unsigned int*)l,
                    16, 0, 0);
            }
        }
        const float* bufc = &buf[cur][0];
#else
        float4 p0, p1, p2, p3;
        if (c < 15) {
            const float4* s4 = (const float4*)(cb + (size_t)(c + 1) * CHF);
            p0 = s4[0 * 256 + tid]; p1 = s4[1 * 256 + tid];
            p2 = s4[2 * 256 + tid]; p3 = s4[3 * 256 + tid];
        }
        const float* bufc = &buf[cur][0];
#endif
#pragma unroll 2
        for (int g = 0; g < 8; ++g) {
            const int eb = e0 + 4 * g;                 // wave-uniform
            const float* c0p = bufc + (size_t)(eb + 0) * NK;
            const float* c1p = bufc + (size_t)(eb + 1) * NK;
            const float* c2p = bufc + (size_t)(eb + 2) * NK;
            const float* c3p = bufc + (size_t)(eb + 3) * NK;
            float a00 = 0.f, a01 = 0.f, a02 = 0.f, a03 = 0.f;
            float a10 = 0.f, a11 = 0.f, a12 = 0.f, a13 = 0.f;
            float a20 = 0.f, a21 = 0.f, a22 = 0.f, a23 = 0.f;
            float a30 = 0.f, a31 = 0.f, a32 = 0.f, a33 = 0.f;
#pragma unroll
            for (int k = 0; k < NK; k += 4) {
                float4 cv0 = *(const float4*)(c0p + k);
                float4 cv1 = *(const float4*)(c1p + k);
                float4 cv2 = *(const float4*)(c2p + k);
                float4 cv3 = *(const float4*)(c3p + k);
                CHAINS(a00, a01, a02, a03, cv0)
                CHAINS(a10, a11, a12, a13, cv1)
                CHAINS(a20, a21, a22, a23, cv2)
                CHAINS(a30, a31, a32, a33, cv3)
            }
            // finish in ascending j (first-min semantics preserved)
            FIN(a00, a01, a02, a03, 0)
            FIN(a10, a11, a12, a13, 1)
            FIN(a20, a21, a22, a23, 2)
            FIN(a30, a31, a32, a33, 3)
        }
#if !HAS_GLL
        if (c < 15) {   // write-late into the other buffer
            float4* d4 = (float4*)&buf[cur ^ 1][0];
            d4[0 * 256 + tid] = p0; d4[1 * 256 + tid] = p1;
            d4[2 * 256 + tid] = p2; d4[3 * 256 + tid] = p3;
        }
#endif
        __syncthreads();   // drains vmcnt: staged chunk complete in LDS
    }

    // ---- combine the two half-scans (reuse buf; last barrier already ran) ----
    float* s_d = &buf[0][0];              // 256 floats
    int*   s_j = (int*)&buf[0][512];      // 256 ints
    s_d[tid] = best; s_j[tid] = bidx;
    __syncthreads();
    if (tid < 128) {
        float dB = s_d[tid + 128]; int jB = s_j[tid + 128];
        int take = (dB < best) || (dB == best && jB < bidx);
        int j = take ? jB : bidx;
        s_idx[tid] = j;
        out_idx[rowb + tid] = (float)j;
    }
    __syncthreads();

    // ---- phase C: fully coalesced gathers (v3-verbatim) ----
    {   // z_q: 128 rows * 64 = 32 KB contiguous writes, cb rows L2-hot
        float* dst = out_zq + rowb * NK;
#pragma unroll
        for (int i = 0; i < 8; ++i) {
            int off = i * 1024 + tid * 4;
            *(float4*)(dst + off) =
                *(const float4*)(cb + (size_t)s_idx[off >> 6] * NK + (off & 63));
        }
    }
    {   // x_recon: 128 rows * 512 = 256 KB contiguous writes, C_dec L2-hot
        float* dst = out_rec + rowb * ND;
#pragma unroll 4
        for (int i = 0; i < 64; ++i) {
            int off = i * 1024 + tid * 4;
            *(float4*)(dst + off) =
                *(const float4*)(C_dec + (size_t)s_idx[off >> 9] * ND + (off & 511));
        }
    }
}

// ---------------------------------------------------------------------------
// Fallback (no workspace): v1 monolithic kernel, kept verbatim for safety.
// ---------------------------------------------------------------------------
__global__ __launch_bounds__(256, 2) void vq_main_old(
    const float* __restrict__ x, const float* __restrict__ U,
    const float* __restrict__ cb, float* __restrict__ out)
{
    const int r = blockIdx.x * 256 + threadIdx.x;
    const float4* __restrict__ x4 = (const float4*)(x + (size_t)r * ND);

    float z[NK];
#pragma unroll
    for (int j = 0; j < NK; ++j) z[j] = 0.f;

    for (int k4 = 0; k4 < ND / 4; ++k4) {
        float4 xv = x4[k4];
        const float* __restrict__ u = U + (size_t)(4 * k4) * NK;
#pragma unroll
        for (int j = 0; j < NK; ++j) z[j] = fmaf(u[j], xv.x, z[j]);
        u += NK;
#pragma unroll
        for (int j = 0; j < NK; ++j) z[j] = fmaf(u[j], xv.y, z[j]);
        u += NK;
#pragma unroll
        for (int j = 0; j < NK; ++j) z[j] = fmaf(u[j], xv.z, z[j]);
        u += NK;
#pragma unroll
        for (int j = 0; j < NK; ++j) z[j] = fmaf(u[j], xv.w, z[j]);
    }

    float best = 3.4e38f;
    int bidx = 0;
    for (int j = 0; j < NCB; ++j) {
        const float* __restrict__ c = cb + (size_t)j * NK;
        float a0 = 0.f, a1 = 0.f, a2 = 0.f, a3 = 0.f;
        float s0 = 0.f, s1 = 0.f, s2 = 0.f, s3 = 0.f;
#pragma unroll
        for (int k = 0; k < NK; k += 4) {
            a0 = fmaf(z[k + 0], c[k + 0], a0);
            a1 = fmaf(z[k + 1], c[k + 1], a1);
            a2 = fmaf(z[k + 2], c[k + 2], a2);
            a3 = fmaf(z[k + 3], c[k + 3], a3);
            s0 = fmaf(c[k + 0], c[k + 0], s0);
            s1 = fmaf(c[k + 1], c[k + 1], s1);
            s2 = fmaf(c[k + 2], c[k + 2], s2);
            s3 = fmaf(c[k + 3], c[k + 3], s3);
        }
        float dot = (a0 + a1) + (a2 + a3);
        float csq = (s0 + s1) + (s2 + s3);
        float dist = fmaf(-2.f, dot, csq);
        if (dist < best) { best = dist; bidx = j; }
    }

    float* __restrict__ out_recon = out;
    float* __restrict__ out_z   = out + (size_t)NB * ND;
    float* __restrict__ out_zq  = out_z + (size_t)NB * NK;
    float* __restrict__ out_idx = out_zq + (size_t)NB * NK;

    float4* __restrict__ oz = (float4*)(out_z + (size_t)r * NK);
#pragma unroll
    for (int q = 0; q < NK / 4; ++q)
        oz[q] = make_float4(z[4 * q], z[4 * q + 1], z[4 * q + 2], z[4 * q + 3]);

    float zq[NK];
    const float4* __restrict__ crow4 = (const float4*)(cb + (size_t)bidx * NK);
    float4* __restrict__ ozq = (float4*)(out_zq + (size_t)r * NK);
#pragma unroll
    for (int q = 0; q < NK / 4; ++q) {
        float4 v = crow4[q];
        ozq[q] = v;
        zq[4 * q] = v.x; zq[4 * q + 1] = v.y; zq[4 * q + 2] = v.z; zq[4 * q + 3] = v.w;
    }

    out_idx[r] = (float)bidx;

    float4* __restrict__ orc = (float4*)(out_recon + (size_t)r * ND);
    for (int d = 0; d < ND; d += 4) {
        float r0 = 0.f, r1 = 0.f, r2 = 0.f, r3 = 0.f;
        const float* __restrict__ u0 = U + (size_t)(d + 0) * NK;
        const float* __restrict__ u1 = U + (size_t)(d + 1) * NK;
        const float* __restrict__ u2 = U + (size_t)(d + 2) * NK;
        const float* __restrict__ u3 = U + (size_t)(d + 3) * NK;
#pragma unroll
        for (int k = 0; k < NK; ++k) {
            r0 = fmaf(zq[k], u0[k], r0);
            r1 = fmaf(zq[k], u1[k], r1);
            r2 = fmaf(zq[k], u2[k], r2);
            r3 = fmaf(zq[k], u3[k], r3);
        }
        orc[d / 4] = make_float4(r0, r1, r2, r3);
    }
}

extern "C" void kernel_launch(void* const* d_in, const int* in_sizes, int n_in,
                              void* d_out, int out_size, void* d_ws, size_t ws_size,
                              hipStream_t stream) {
    const float* x  = (const float*)d_in[0];
    const float* U  = (const float*)d_in[1];
    const float* cb = (const float*)d_in[2];
    float* out = (float*)d_out;

    const size_t need = (size_t)NCB * ND * sizeof(float) + NCB * sizeof(float);
    if (ws_size >= need) {
        float* C_dec = (float*)d_ws;
        float* c_sq  = C_dec + (size_t)NCB * ND;
        vq_precompute<<<(NCB * ND) / 256, 256, 0, stream>>>(U, cb, C_dec, c_sq);
        vq_main4<<<NB / RPB2, TPB, 0, stream>>>(x, U, cb, c_sq, C_dec, out);
    } else {
        vq_main_old<<<NB / 256, 256, 0, stream>>>(x, U, cb, out);
    }
}

// Round 4
// 812.430 us; speedup vs baseline: 1.6431x; 1.6431x over previous
//
#include <hip/hip_runtime.h>

#define NB 131072
#define ND 512
#define NK 64
#define NCB 1024

#define TPB 256
#define RPB2 128            // rows per block

#if defined(__has_builtin)
#if __has_builtin(__builtin_amdgcn_global_load_lds)
#define HAS_GLL 1
#else
#define HAS_GLL 0
#endif
#else
#define HAS_GLL 0
#endif

#if HAS_GLL
#define GLL16(gp, lp) __builtin_amdgcn_global_load_lds( \
    (const __attribute__((address_space(1))) unsigned int*)(gp), \
    (__attribute__((address_space(3))) unsigned int*)(lp), 16, 0, 0)
#endif

// Swizzled LDS word for element (row r, col k) of a [128][64] tile.
// XOR of r's bits [6:3] (low 3) into k's bits [4:2] keeps b128 alignment and
// turns the 8-row-strided lane pattern into a 2-way (free) bank pattern.
__device__ __forceinline__ int zword(int r, int k) {
    return (r << 6) + (k ^ (((r >> 3) & 7) << 2));
}

// ---------------------------------------------------------------------------
// Precompute: C_dec[c][d] = sum_k cb[c,k] * U[d,k]   (decoded codebook, 2 MB)
//             c_sq[c]     = ||cb[c]||^2     (unchanged from passing kernel)
// ---------------------------------------------------------------------------
__global__ __launch_bounds__(256) void vq_precompute(
    const float* __restrict__ U, const float* __restrict__ cb,
    float* __restrict__ C_dec, float* __restrict__ c_sq)
{
    int t = blockIdx.x * 256 + threadIdx.x;
    int c = t >> 9;
    int d = t & (ND - 1);
    const float* __restrict__ crow = cb + (size_t)c * NK;
    const float* __restrict__ urow = U + (size_t)d * NK;
    float a0 = 0.f, a1 = 0.f, a2 = 0.f, a3 = 0.f;
#pragma unroll
    for (int k = 0; k < NK; k += 4) {
        a0 = fmaf(crow[k + 0], urow[k + 0], a0);
        a1 = fmaf(crow[k + 1], urow[k + 1], a1);
        a2 = fmaf(crow[k + 2], urow[k + 2], a2);
        a3 = fmaf(crow[k + 3], urow[k + 3], a3);
    }
    C_dec[t] = (a0 + a1) + (a2 + a3);
    if (d == 0) {
        float s0 = 0.f, s1 = 0.f, s2 = 0.f, s3 = 0.f;
#pragma unroll
        for (int k = 0; k < NK; k += 4) {
            s0 = fmaf(crow[k + 0], crow[k + 0], s0);
            s1 = fmaf(crow[k + 1], crow[k + 1], s1);
            s2 = fmaf(crow[k + 2], crow[k + 2], s2);
            s3 = fmaf(crow[k + 3], crow[k + 3], s3);
        }
        c_sq[c] = (s0 + s1) + (s2 + s3);
    }
}

// ---------------------------------------------------------------------------
// Main v5: LDS-bandwidth-optimized register tiling.
//   Phase A: z = x@U, 8 rows x 4 js per thread (1.5 B/FMA from LDS).
//            d-ascending single fmaf chain -> z bitwise == v1.
//   Phase B: 8 rows x 8 entries per thread (1.0 B/FMA from LDS).
//   z tile [128][64] swizzled in LDS; cb chunks (128 entries) single-buffered
//   with reg-prefetch from pre-swizzled global positions; U chunks dbuf'd
//   via global_load_lds.  (dist,index)-lexicographic reduce == first-min.
// ---------------------------------------------------------------------------
__global__ __launch_bounds__(256, 2) void vq_main5(
    const float* __restrict__ x, const float* __restrict__ U,
    const float* __restrict__ cb, const float* __restrict__ c_sq,
    const float* __restrict__ C_dec, float* __restrict__ out)
{
    __shared__ __align__(16) float xz[RPB2 * NK];     // 32 KB: x chunks, then z
    __shared__ __align__(16) float cbu[2 * 4096];     // 32 KB: U dbuf / cb chunk / reduce
    __shared__ float csq_lds[NCB];                    // 4 KB
    __shared__ int   s_idx[RPB2];                     // 0.5 KB

    const int tid = threadIdx.x;
    const int tr  = tid & 15;     // rows 8*tr .. 8*tr+7
    const int te  = tid >> 4;     // 0..15: js 4*te.. (A), entries 8*te.. (B)
    const size_t rowb = (size_t)blockIdx.x * RPB2;

    float* const out_rec = out;                                   // B*D
    float* const out_z   = out + (size_t)NB * ND;                 // B*K
    float* const out_zq  = out_z + (size_t)NB * NK;               // B*K
    float* const out_idx = out_zq + (size_t)NB * NK;              // B

    // ---- prologue: csq, x chunk 0 (regs->LDS swizzled), U chunk 0 (GLL) ----
    ((float4*)csq_lds)[tid] = ((const float4*)c_sq)[tid];

    float4 stg[8];
#pragma unroll
    for (int i = 0; i < 8; ++i) {
        int f4 = tid + 256 * i;            // linear float4 idx in 32 KB chunk
        int r = f4 >> 4, c4 = f4 & 15;
        stg[i] = *(const float4*)(x + (rowb + r) * ND + c4 * 4);
    }
#if HAS_GLL
#pragma unroll
    for (int q = 0; q < 4; ++q) {
        const float* g = U + (size_t)(q * 256 + tid) * 4;
        float* l = &cbu[(q * 256 + (tid >> 6) * 64) * 4];
        GLL16(g, l);
    }
#else
#pragma unroll
    for (int q = 0; q < 4; ++q)
        ((float4*)&cbu[0])[q * 256 + tid] = ((const float4*)U)[q * 256 + tid];
#endif
#pragma unroll
    for (int i = 0; i < 8; ++i) {
        int f4 = tid + 256 * i;
        int r = f4 >> 4, c4 = f4 & 15;
        *(float4*)&xz[zword(r, c4 * 4)] = stg[i];
    }
    __syncthreads();

    // ---------------- Phase A: z = x @ U, tile 8r x 4j ---------------------
    float accA[8][4];
#pragma unroll
    for (int rr = 0; rr < 8; ++rr)
#pragma unroll
        for (int jj = 0; jj < 4; ++jj) accA[rr][jj] = 0.f;

    for (int dc = 0; dc < 8; ++dc) {
        const int ubuf = dc & 1;
        if (dc < 7) {   // issue next x chunk (regs) + next U chunk (GLL) early
#pragma unroll
            for (int i = 0; i < 8; ++i) {
                int f4 = tid + 256 * i;
                int r = f4 >> 4, c4 = f4 & 15;
                stg[i] = *(const float4*)(x + (rowb + r) * ND + (dc + 1) * 64 + c4 * 4);
            }
#if HAS_GLL
#pragma unroll
            for (int q = 0; q < 4; ++q) {
                const float* g = U + (size_t)(dc + 1) * 4096 + (size_t)(q * 256 + tid) * 4;
                float* l = &cbu[(ubuf ^ 1) * 4096 + (q * 256 + (tid >> 6) * 64) * 4];
                GLL16(g, l);
            }
#endif
        }
        const float* ub = &cbu[ubuf * 4096];
#pragma unroll 2
        for (int dq = 0; dq < 16; ++dq) {
            float xs[8][4];
#pragma unroll
            for (int rr = 0; rr < 8; ++rr) {
                float4 v = *(const float4*)&xz[zword(8 * tr + rr, dq * 4)];
                xs[rr][0] = v.x; xs[rr][1] = v.y; xs[rr][2] = v.z; xs[rr][3] = v.w;
            }
            float us[4][4];
#pragma unroll
            for (int i = 0; i < 4; ++i) {
                float4 v = *(const float4*)(ub + (dq * 4 + i) * 64 + 4 * te);
                us[i][0] = v.x; us[i][1] = v.y; us[i][2] = v.z; us[i][3] = v.w;
            }
            // i ascending => d ascending: bitwise == v1's z chain
#pragma unroll
            for (int i = 0; i < 4; ++i)
#pragma unroll
                for (int rr = 0; rr < 8; ++rr)
#pragma unroll
                    for (int jj = 0; jj < 4; ++jj)
                        accA[rr][jj] = fmaf(xs[rr][i], us[i][jj], accA[rr][jj]);
        }
        __syncthreads();
#if !HAS_GLL
        if (dc < 7) {
#pragma unroll
            for (int q = 0; q < 4; ++q)
                ((float4*)&cbu[(ubuf ^ 1) * 4096])[q * 256 + tid] =
                    ((const float4*)(U + (size_t)(dc + 1) * 4096))[q * 256 + tid];
        }
#endif
        if (dc < 7) {
#pragma unroll
            for (int i = 0; i < 8; ++i) {
                int f4 = tid + 256 * i;
                int r = f4 >> 4, c4 = f4 & 15;
                *(float4*)&xz[zword(r, c4 * 4)] = stg[i];
            }
            __syncthreads();
        }
    }

    // ---- A->B: issue cb chunk0 (GLL, pre-swizzled source); z -> xz ----
#if HAS_GLL
#pragma unroll
    for (int q = 0; q < 8; ++q) {
        int idx = q * 256 + tid;             // linear dest float4 idx (0..2047)
        int e = idx >> 4, w4 = idx & 15;
        int kq = w4 ^ ((e >> 3) & 7);        // involution: source k-quad
        const float* g = cb + (size_t)e * 64 + kq * 4;
        float* l = &cbu[(q * 256 + (tid >> 6) * 64) * 4];
        GLL16(g, l);
    }
#else
#pragma unroll
    for (int q = 0; q < 8; ++q) {
        int idx = q * 256 + tid;
        int e = idx >> 4, w4 = idx & 15;
        int kq = w4 ^ ((e >> 3) & 7);
        stg[q] = *(const float4*)(cb + (size_t)e * 64 + kq * 4);
    }
#pragma unroll
    for (int q = 0; q < 8; ++q)
        ((float4*)cbu)[q * 256 + tid] = stg[q];
#endif
#pragma unroll
    for (int rr = 0; rr < 8; ++rr) {
        int r = 8 * tr + rr;
        float4 v = make_float4(accA[rr][0], accA[rr][1], accA[rr][2], accA[rr][3]);
        *(float4*)&xz[zword(r, 4 * te)] = v;
    }
    __syncthreads();

    // ---------------- Phase B: argmin, tile 8r x 8e ------------------------
    float best[8];
    int   bidx[8];
#pragma unroll
    for (int rr = 0; rr < 8; ++rr) { best[rr] = 3.4e38f; bidx[rr] = 0; }

    for (int cc = 0; cc < 8; ++cc) {
        if (cc < 7) {   // prefetch next 128-entry chunk from pre-swizzled pos
#pragma unroll
            for (int q = 0; q < 8; ++q) {
                int idx = q * 256 + tid;
                int e = idx >> 4, w4 = idx & 15;
                int kq = w4 ^ ((e >> 3) & 7);
                stg[q] = *(const float4*)(cb + (size_t)(cc + 1) * 8192 +
                                          (size_t)e * 64 + kq * 4);
            }
        }
        float accB[8][8];
#pragma unroll
        for (int rr = 0; rr < 8; ++rr)
#pragma unroll
            for (int ee = 0; ee < 8; ++ee) accB[rr][ee] = 0.f;

#pragma unroll 2
        for (int kq = 0; kq < 16; ++kq) {
            float zs[8][4];
#pragma unroll
            for (int rr = 0; rr < 8; ++rr) {
                float4 v = *(const float4*)&xz[zword(8 * tr + rr, kq * 4)];
                zs[rr][0] = v.x; zs[rr][1] = v.y; zs[rr][2] = v.z; zs[rr][3] = v.w;
            }
            float cs[8][4];
#pragma unroll
            for (int ee = 0; ee < 8; ++ee) {
                float4 v = *(const float4*)&cbu[zword(8 * te + ee, kq * 4)];
                cs[ee][0] = v.x; cs[ee][1] = v.y; cs[ee][2] = v.z; cs[ee][3] = v.w;
            }
#pragma unroll
            for (int rr = 0; rr < 8; ++rr)
#pragma unroll
                for (int ee = 0; ee < 8; ++ee) {
                    accB[rr][ee] = fmaf(zs[rr][0], cs[ee][0], accB[rr][ee]);
                    accB[rr][ee] = fmaf(zs[rr][1], cs[ee][1], accB[rr][ee]);
                    accB[rr][ee] = fmaf(zs[rr][2], cs[ee][2], accB[rr][ee]);
                    accB[rr][ee] = fmaf(zs[rr][3], cs[ee][3], accB[rr][ee]);
                }
        }
        // finish: ascending ee => ascending global j per thread
#pragma unroll
        for (int ee = 0; ee < 8; ++ee) {
            int j = cc * 128 + 8 * te + ee;
            float csq = csq_lds[j];
#pragma unroll
            for (int rr = 0; rr < 8; ++rr) {
                float dist = fmaf(-2.f, accB[rr][ee], csq);
                if (dist < best[rr]) { best[rr] = dist; bidx[rr] = j; }
            }
        }
        __syncthreads();
        if (cc < 7) {
#pragma unroll
            for (int q = 0; q < 8; ++q)
                ((float4*)cbu)[q * 256 + tid] = stg[q];   // data pre-swizzled
            __syncthreads();
        }
    }

    // ---- (dist, index) lexicographic reduce over the 16 te-threads --------
    {
        float* red_d = &cbu[0];               // [16][132] padded
        int*   red_j = (int*)&cbu[16 * 132];  // [16][132]
#pragma unroll
        for (int rr = 0; rr < 8; ++rr) {
            int r = 8 * tr + rr;
            red_d[te * 132 + r] = best[rr];
            red_j[te * 132 + r] = bidx[rr];
        }
        __syncthreads();
        if (tid < RPB2) {
            int r = tid;
            float bd = red_d[r]; int bj = red_j[r];
#pragma unroll
            for (int t2 = 1; t2 < 16; ++t2) {
                float d2 = red_d[t2 * 132 + r]; int j2 = red_j[t2 * 132 + r];
                if (d2 < bd || (d2 == bd && j2 < bj)) { bd = d2; bj = j2; }
            }
            s_idx[r] = bj;
            out_idx[rowb + r] = (float)bj;
        }
        __syncthreads();
    }

    // ---------------- Phase C: fully coalesced epilogue --------------------
    {   // z: LDS (unswizzle) -> global, 32 KB contiguous
        float* dst = out_z + rowb * NK;
#pragma unroll
        for (int i = 0; i < 8; ++i) {
            int f4 = tid + 256 * i;
            int r = f4 >> 4, kq = f4 & 15;
            *(float4*)(dst + f4 * 4) = *(const float4*)&xz[zword(r, kq * 4)];
        }
    }
    {   // z_q: gather cb rows (L2-hot), contiguous writes
        float* dst = out_zq + rowb * NK;
#pragma unroll
        for (int i = 0; i < 8; ++i) {
            int off = i * 1024 + tid * 4;
            *(float4*)(dst + off) =
                *(const float4*)(cb + (size_t)s_idx[off >> 6] * NK + (off & 63));
        }
    }
    {   // x_recon: gather C_dec rows (L2-hot), 256 KB contiguous writes
        float* dst = out_rec + rowb * ND;
#pragma unroll 4
        for (int i = 0; i < 64; ++i) {
            int off = i * 1024 + tid * 4;
            *(float4*)(dst + off) =
                *(const float4*)(C_dec + (size_t)s_idx[off >> 9] * ND + (off & 511));
        }
    }
}

// ---------------------------------------------------------------------------
// Fallback (no workspace): v1 monolithic kernel, kept verbatim for safety.
// ---------------------------------------------------------------------------
__global__ __launch_bounds__(256, 2) void vq_main_old(
    const float* __restrict__ x, const float* __restrict__ U,
    const float* __restrict__ cb, float* __restrict__ out)
{
    const int r = blockIdx.x * 256 + threadIdx.x;
    const float4* __restrict__ x4 = (const float4*)(x + (size_t)r * ND);

    float z[NK];
#pragma unroll
    for (int j = 0; j < NK; ++j) z[j] = 0.f;

    for (int k4 = 0; k4 < ND / 4; ++k4) {
        float4 xv = x4[k4];
        const float* __restrict__ u = U + (size_t)(4 * k4) * NK;
#pragma unroll
        for (int j = 0; j < NK; ++j) z[j] = fmaf(u[j], xv.x, z[j]);
        u += NK;
#pragma unroll
        for (int j = 0; j < NK; ++j) z[j] = fmaf(u[j], xv.y, z[j]);
        u += NK;
#pragma unroll
        for (int j = 0; j < NK; ++j) z[j] = fmaf(u[j], xv.z, z[j]);
        u += NK;
#pragma unroll
        for (int j = 0; j < NK; ++j) z[j] = fmaf(u[j], xv.w, z[j]);
    }

    float best = 3.4e38f;
    int bidx = 0;
    for (int j = 0; j < NCB; ++j) {
        const float* __restrict__ c = cb + (size_t)j * NK;
        float a0 = 0.f, a1 = 0.f, a2 = 0.f, a3 = 0.f;
        float s0 = 0.f, s1 = 0.f, s2 = 0.f, s3 = 0.f;
#pragma unroll
        for (int k = 0; k < NK; k += 4) {
            a0 = fmaf(z[k + 0], c[k + 0], a0);
            a1 = fmaf(z[k + 1], c[k + 1], a1);
            a2 = fmaf(z[k + 2], c[k + 2], a2);
            a3 = fmaf(z[k + 3], c[k + 3], a3);
            s0 = fmaf(c[k + 0], c[k + 0], s0);
            s1 = fmaf(c[k + 1], c[k + 1], s1);
            s2 = fmaf(c[k + 2], c[k + 2], s2);
            s3 = fmaf(c[k + 3], c[k + 3], s3);
        }
        float dot = (a0 + a1) + (a2 + a3);
        float csq = (s0 + s1) + (s2 + s3);
        float dist = fmaf(-2.f, dot, csq);
        if (dist < best) { best = dist; bidx = j; }
    }

    float* __restrict__ out_recon = out;
    float* __restrict__ out_z   = out + (size_t)NB * ND;
    float* __restrict__ out_zq  = out_z + (size_t)NB * NK;
    float* __restrict__ out_idx = out_zq + (size_t)NB * NK;

    float4* __restrict__ oz = (float4*)(out_z + (size_t)r * NK);
#pragma unroll
    for (int q = 0; q < NK / 4; ++q)
        oz[q] = make_float4(z[4 * q], z[4 * q + 1], z[4 * q + 2], z[4 * q + 3]);

    float zq[NK];
    const float4* __restrict__ crow4 = (const float4*)(cb + (size_t)bidx * NK);
    float4* __restrict__ ozq = (float4*)(out_zq + (size_t)r * NK);
#pragma unroll
    for (int q = 0; q < NK / 4; ++q) {
        float4 v = crow4[q];
        ozq[q] = v;
        zq[4 * q] = v.x; zq[4 * q + 1] = v.y; zq[4 * q + 2] = v.z; zq[4 * q + 3] = v.w;
    }

    out_idx[r] = (float)bidx;

    float4* __restrict__ orc = (float4*)(out_recon + (size_t)r * ND);
    for (int d = 0; d < ND; d += 4) {
        float r0 = 0.f, r1 = 0.f, r2 = 0.f, r3 = 0.f;
        const float* __restrict__ u0 = U + (size_t)(d + 0) * NK;
        const float* __restrict__ u1 = U + (size_t)(d + 1) * NK;
        const float* __restrict__ u2 = U + (size_t)(d + 2) * NK;
        const float* __restrict__ u3 = U + (size_t)(d + 3) * NK;
#pragma unroll
        for (int k = 0; k < NK; ++k) {
            r0 = fmaf(zq[k], u0[k], r0);
            r1 = fmaf(zq[k], u1[k], r1);
            r2 = fmaf(zq[k], u2[k], r2);
            r3 = fmaf(zq[k], u3[k], r3);
        }
        orc[d / 4] = make_float4(r0, r1, r2, r3);
    }
}

extern "C" void kernel_launch(void* const* d_in, const int* in_sizes, int n_in,
                              void* d_out, int out_size, void* d_ws, size_t ws_size,
                              hipStream_t stream) {
    const float* x  = (const float*)d_in[0];
    const float* U  = (const float*)d_in[1];
    const float* cb = (const float*)d_in[2];
    float* out = (float*)d_out;

    const size_t need = (size_t)NCB * ND * sizeof(float) + NCB * sizeof(float);
    if (ws_size >= need) {
        float* C_dec = (float*)d_ws;
        float* c_sq  = C_dec + (size_t)NCB * ND;
        vq_precompute<<<(NCB * ND) / 256, 256, 0, stream>>>(U, cb, C_dec, c_sq);
        vq_main5<<<NB / RPB2, TPB, 0, stream>>>(x, U, cb, c_sq, C_dec, out);
    } else {
        vq_main_old<<<NB / 256, 256, 0, stream>>>(x, U, cb, out);
    }
}